// Round 14
// baseline (129.473 us; speedup 1.0000x reference)
//
#include <hip/hip_runtime.h>

// VQ-VAE forward: N=131072 rows (D=64), K=512 codes.
// Outputs flat: [loss(1) | quantized_st(8388608, NCHW) | perplexity(1) | encodings(131072x512)]
//
// R14: fuse the encodings stream INTO vq_dist (overlap, not serialize).
// R13 budget: dist ~65 (memory pipes idle) + enc ~45 (VALU idle) run serially; the split
// itself never helped (R11~R10 — gains were atomics+slimming). Fusion rules learned R8/R12:
//   - barriers stay lgkmcnt-only; enc slab stores are fire-and-forget (drain under the next
//     group's staging/MFMA; kernel-end drain guarantees completeness). NO vmcnt(0) anywhere.
//   - no atomics in the hot kernel: counts via a 64-block LDS-histogram kernel over idx
//     (131K LDS atomics + 32K spread global atomics, ~4us).
// Enc write pattern = vq_enc's proven coalesced c*512+tid float2 stream, fkb[64] staged in
// LDS (one extra lgkm barrier b3). Math identical to R13 (absmax ~1.0 regime).

#define OFF_Q    1
#define OFF_PERP 8388609
#define OFF_ENC  8388610

typedef float accf4 __attribute__((ext_vector_type(4)));
typedef short bfrag8 __attribute__((ext_vector_type(8)));

__device__ __forceinline__ unsigned short f2bf(float f) {
    union { float f; unsigned u; } v; v.f = f;
    unsigned r = v.u + 0x7FFFu + ((v.u >> 16) & 1u);   // RNE
    return (unsigned short)(r >> 16);
}

__device__ __forceinline__ void lds_barrier() {
    asm volatile("s_waitcnt lgkmcnt(0)" ::: "memory");
    __builtin_amdgcn_s_barrier();
    asm volatile("" ::: "memory");
}

__global__ __launch_bounds__(512) void vq_prep(const float* __restrict__ emb,
                                               float* __restrict__ Bk,
                                               unsigned* __restrict__ counts) {
    int k = threadIdx.x;
    const float4* e4 = reinterpret_cast<const float4*>(emb) + k * 16;
    float s = 0.f;
    #pragma unroll
    for (int i = 0; i < 16; ++i) {
        float4 v = e4[i];
        s += v.x * v.x + v.y * v.y + v.z * v.z + v.w * v.w;
    }
    Bk[k] = s;
    counts[k] = 0u;
}

// ---- vq_dist: MFMA distances + argmin + quantized + loss + idx + FUSED enc stream ----
__global__ __launch_bounds__(512, 4) void vq_dist(const float* __restrict__ in,
                                                  const float* __restrict__ emb,
                                                  const float* __restrict__ Bk,
                                                  int* __restrict__ idx,
                                                  float* __restrict__ lossPart,
                                                  float* __restrict__ out) {
    __shared__ __align__(16) unsigned short xB[64 * 72];  // X bf16 [row][k-ch], pad 72
    __shared__ float sdw[8][64];                          // per-wave best dist
    __shared__ int   skw[8][64];                          // per-wave best k
    __shared__ int   fkb[64];                             // final fk per row (enc writes)
    __shared__ float lossW[8];                            // per-wave loss partials

    const int tid  = (int)threadIdx.x;
    const int lane = tid & 63;
    const int v    = __builtin_amdgcn_readfirstlane(tid >> 6);  // wave 0..7
    const int q    = lane >> 4;   // quarter-wave 0..3
    const int cidx = lane & 15;

    // E A-fragments for this wave's 64 codes (once per kernel): 32 VGPRs.
    // A layout [R10 HW-verified]: row m = cidx (code within 16-tile), k = q*8+i (+ks*32).
    bfrag8 efr[4][2];
    #pragma unroll
    for (int tn = 0; tn < 4; ++tn) {
        #pragma unroll
        for (int ks = 0; ks < 2; ++ks) {
            const float* ep = emb + (size_t)(v * 64 + tn * 16 + cidx) * 64 + ks * 32 + q * 8;
            float4 e0 = *reinterpret_cast<const float4*>(ep);
            float4 e1 = *reinterpret_cast<const float4*>(ep + 4);
            bfrag8 b;
            b[0] = (short)f2bf(e0.x); b[1] = (short)f2bf(e0.y);
            b[2] = (short)f2bf(e0.z); b[3] = (short)f2bf(e0.w);
            b[4] = (short)f2bf(e1.x); b[5] = (short)f2bf(e1.y);
            b[6] = (short)f2bf(e1.z); b[7] = (short)f2bf(e1.w);
            efr[tn][ks] = b;
        }
    }
    // ||e_k||^2 for this lane's 16 candidate codes: 16 VGPRs.
    float4 Bn[4];
    #pragma unroll
    for (int tn = 0; tn < 4; ++tn)
        Bn[tn] = *reinterpret_cast<const float4*>(&Bk[v * 64 + tn * 16 + q * 4]);
    const int kbaseLane = v * 64 + q * 4;

    float lacc = 0.f;

    #pragma unroll 1
    for (int g = 0; g < 4; ++g) {
        const int gab = (int)blockIdx.x * 4 + g;     // row-group 0..2047 = b*64+h
        const int bb  = gab >> 6;
        const int hh  = gab & 63;
        const size_t rowBase = (size_t)bb * 262144 + (size_t)hh * 64 + (size_t)lane;

        // stage x: wave v loads channels [v*8, v*8+8); one ds_write_b128 per thread
        float xs[8];
        bfrag8 xpk;
        #pragma unroll
        for (int cc = 0; cc < 8; ++cc) {
            const float val = in[rowBase + (size_t)(v * 8 + cc) * 4096];
            xs[cc] = val;
            xpk[cc] = (short)f2bf(val);
        }
        *reinterpret_cast<bfrag8*>(&xB[lane * 72 + v * 8]) = xpk;
        lds_barrier();   // b1: xB staged  [lgkm-only; prior group's enc stores keep draining]

        // per 16-row tile: C = E.X^T, lane-local argmin over 16 candidates
        #pragma unroll
        for (int rt = 0; rt < 4; ++rt) {
            const bfrag8 x0 = *reinterpret_cast<const bfrag8*>(&xB[(rt * 16 + cidx) * 72 + q * 8]);
            const bfrag8 x1 = *reinterpret_cast<const bfrag8*>(&xB[(rt * 16 + cidx) * 72 + 32 + q * 8]);
            accf4 acc[4];
            #pragma unroll
            for (int tn = 0; tn < 4; ++tn) {
                acc[tn] = (accf4){0.f, 0.f, 0.f, 0.f};
                acc[tn] = __builtin_amdgcn_mfma_f32_16x16x32_bf16(efr[tn][0], x0, acc[tn], 0, 0, 0);
                acc[tn] = __builtin_amdgcn_mfma_f32_16x16x32_bf16(efr[tn][1], x1, acc[tn], 0, 0, 0);
            }
            float best = 3.4e38f; int bk = kbaseLane;
            #pragma unroll
            for (int tn = 0; tn < 4; ++tn) {
                #pragma unroll
                for (int r = 0; r < 4; ++r) {
                    const float Bj = (r == 0) ? Bn[tn].x : (r == 1) ? Bn[tn].y : (r == 2) ? Bn[tn].z : Bn[tn].w;
                    const float d = Bj - 2.0f * acc[tn][r];
                    if (d < best) { best = d; bk = kbaseLane + tn * 16 + r; }
                }
            }
            #pragma unroll
            for (int s = 16; s <= 32; s <<= 1) {
                const float od = __shfl_xor(best, s);
                const int   ok = __shfl_xor(bk, s);
                if (od < best || (od == best && ok < bk)) { best = od; bk = ok; }
            }
            if (q == 0) {
                sdw[v][rt * 16 + cidx] = best;
                skw[v][rt * 16 + cidx] = bk;
            }
        }
        lds_barrier();   // b2: argmins shared

        // final argmin for row = lane (all waves compute identically)
        float fd = sdw[0][lane];
        int   fk = skw[0][lane];
        #pragma unroll
        for (int vv = 1; vv < 8; ++vv) {
            const float dv = sdw[vv][lane];
            const int   kv = skw[vv][lane];
            if (dv < fd) { fd = dv; fk = kv; }
        }
        if (v == 0) {
            idx[gab * 64 + lane] = fk;
            fkb[lane] = fk;
        }

        // epilogue: quantized + loss (thread's own row = lane)
        const float* __restrict__ eq = emb + (size_t)fk * 64;
        #pragma unroll
        for (int cc = 0; cc < 8; ++cc) {
            const int c = v * 8 + cc;
            const float qv = eq[c];
            const float dd = qv - xs[cc];
            lacc += dd * dd;
            out[OFF_Q + rowBase + (size_t)c * 4096] = xs[cc] + dd;
        }
        lds_barrier();   // b3: fkb visible  [lgkm-only]

        // FUSED enc stream: group slab = 16384 float2, coalesced c*512+tid pattern,
        // fire-and-forget (drains under next group's staging + MFMA).
        {
            float2* enc2 = reinterpret_cast<float2*>(out + OFF_ENC + (size_t)gab * 32768);
            #pragma unroll
            for (int c = 0; c < 32; ++c) {
                const int p = c * 512 + tid;
                const int row = p >> 8;         // 256 float2 per row
                const int col2 = p & 255;
                const int k = fkb[row];         // LDS broadcast (256 threads same row)
                float2 val;
                val.x = ((k >> 1) == col2 && (k & 1) == 0) ? 1.0f : 0.0f;
                val.y = ((k >> 1) == col2 && (k & 1) == 1) ? 1.0f : 0.0f;
                enc2[p] = val;
            }
        }
        // no further barrier: next b1 (lgkmcnt 0 + s_barrier) orders fkb reads before rewrite.
    }

    // per-block loss partial (deterministic fixed-order; NO atomics)
    #pragma unroll
    for (int off = 32; off > 0; off >>= 1) lacc += __shfl_down(lacc, off);
    if (lane == 0) lossW[v] = lacc;
    lds_barrier();
    if (tid == 0) {
        float s = 0.f;
        #pragma unroll
        for (int i = 0; i < 8; ++i) s += lossW[i];
        lossPart[blockIdx.x] = s;
    }
}

// ---- vq_hist: counts via LDS histogram (64 blocks x 2048 rows) ----
__global__ __launch_bounds__(256) void vq_hist(const int* __restrict__ idx,
                                               unsigned* __restrict__ counts) {
    __shared__ unsigned h[512];
    const int tid = (int)threadIdx.x;
    h[tid] = 0u; h[tid + 256] = 0u;
    __syncthreads();
    const int base = (int)blockIdx.x * 2048;
    #pragma unroll
    for (int i = 0; i < 8; ++i)
        atomicAdd(&h[idx[base + i * 256 + tid]], 1u);
    __syncthreads();
    atomicAdd(&counts[tid], h[tid]);
    atomicAdd(&counts[tid + 256], h[tid + 256]);
}

__global__ __launch_bounds__(512) void vq_fin(const unsigned* __restrict__ counts,
                                              const float* __restrict__ lossPart,
                                              float* __restrict__ out) {
    __shared__ float red[512];
    __shared__ float lr[512];
    int k = threadIdx.x;
    float p = (float)counts[k] * (1.0f / 131072.0f);   // exact: count * 2^-17
    red[k] = p * logf(p + 1e-10f);
    lr[k] = lossPart[k];
    __syncthreads();
    for (int s = 256; s > 0; s >>= 1) {
        if (k < s) { red[k] += red[k + s]; lr[k] += lr[k + s]; }
        __syncthreads();
    }
    if (k == 0) {
        out[OFF_PERP] = expf(-red[0]);
        float mf = lr[0] * (1.0f / 8388608.0f);
        out[0] = mf + 0.25f * mf;   // q_latent + 0.25 * e_latent (identical values)
    }
}

extern "C" void kernel_launch(void* const* d_in, const int* in_sizes, int n_in,
                              void* d_out, int out_size, void* d_ws, size_t ws_size,
                              hipStream_t stream) {
    const float* in  = (const float*)d_in[0];
    // d_in[1] = labels (unused by the reference forward)
    const float* emb = (const float*)d_in[2];
    float* out = (float*)d_out;

    float* Bk        = (float*)d_ws;                      // 512 f32   [0,2048)
    unsigned* counts = (unsigned*)((char*)d_ws + 2048);   // 512 u32   [2048,4096)
    float* lossPart  = (float*)((char*)d_ws + 4096);      // 512 f32   [4096,6144)
    int* idx         = (int*)((char*)d_ws + 8192);        // 131072 i32

    vq_prep<<<1, 512, 0, stream>>>(emb, Bk, counts);
    vq_dist<<<512, 512, 0, stream>>>(in, emb, Bk, idx, lossPart, out);
    vq_hist<<<64, 256, 0, stream>>>(idx, counts);
    vq_fin<<<1, 512, 0, stream>>>(counts, lossPart, out);
}